// Round 9
// baseline (624.424 us; speedup 1.0000x reference)
//
#include <hip/hip_runtime.h>
#include <hip/hip_bf16.h>
#include <math.h>

// Problem constants (fixed by the reference file)
#define BB 2
#define NN 21760
#define CC 256
#define HH 8
#define PP 21760
#define MROWS (BB * NN)   // 43520 query rows
#define VROWS (BB * PP)   // 43520 value rows

typedef __attribute__((ext_vector_type(8))) short bf16x8;
typedef __attribute__((ext_vector_type(4))) float f32x4;

__device__ __forceinline__ unsigned short f2bf(float f) {
  unsigned u = __float_as_uint(f);
  u += 0x7fff + ((u >> 16) & 1);   // RNE
  return (unsigned short)(u >> 16);
}
__device__ __forceinline__ float bf2f(unsigned short s) {
  return __uint_as_float(((unsigned)s) << 16);
}

// ---------------------------------------------------------------------------
// Block-wide sum over 256 threads (4 waves of 64)
// ---------------------------------------------------------------------------
__device__ __forceinline__ float block_sum_256(float v, float* red) {
  #pragma unroll
  for (int o = 1; o < 64; o <<= 1) v += __shfl_xor(v, o, 64);
  int wid = threadIdx.x >> 6;
  int lane = threadIdx.x & 63;
  if (lane == 0) red[wid] = v;
  __syncthreads();
  float s = red[0] + red[1] + red[2] + red[3];
  __syncthreads();
  return s;
}

// ---------------------------------------------------------------------------
// q, v fp32 -> bf16 (row-major, same shape)
// ---------------------------------------------------------------------------
__global__ __launch_bounds__(256) void conv_bf16(
    const float* __restrict__ q, const float* __restrict__ v,
    unsigned short* __restrict__ qb, unsigned short* __restrict__ vb) {
  size_t i = ((size_t)blockIdx.x * 256 + threadIdx.x) * 8;
  float4 a0 = *(const float4*)(q + i);
  float4 a1 = *(const float4*)(q + i + 4);
  ushort4 o0 = {f2bf(a0.x), f2bf(a0.y), f2bf(a0.z), f2bf(a0.w)};
  ushort4 o1 = {f2bf(a1.x), f2bf(a1.y), f2bf(a1.z), f2bf(a1.w)};
  *(ushort4*)(qb + i) = o0;
  *(ushort4*)(qb + i + 4) = o1;
  float4 b0 = *(const float4*)(v + i);
  float4 b1 = *(const float4*)(v + i + 4);
  ushort4 p0 = {f2bf(b0.x), f2bf(b0.y), f2bf(b0.z), f2bf(b0.w)};
  ushort4 p1 = {f2bf(b1.x), f2bf(b1.y), f2bf(b1.z), f2bf(b1.w)};
  *(ushort4*)(vb + i) = p0;
  *(ushort4*)(vb + i + 4) = p1;
}

// ---------------------------------------------------------------------------
// Weights -> transposed bf16 [N][K].  (W_out stays fp32 for VALU out-proj.)
// ---------------------------------------------------------------------------
__global__ __launch_bounds__(256) void prep_all(
    const float* __restrict__ W_off, const float* __restrict__ W_at,
    const float* __restrict__ W_val,
    const float* __restrict__ W1, const float* __restrict__ W2,
    unsigned short* __restrict__ WoffT, unsigned short* __restrict__ WattnT,
    unsigned short* __restrict__ WvalT,
    unsigned short* __restrict__ W1T, unsigned short* __restrict__ W2T) {
  int i = blockIdx.x * 256 + threadIdx.x;
  if (i < 65536) {                    // WoffT[256][256]
    WoffT[i] = f2bf(W_off[(size_t)(i & 255) * 256 + (i >> 8)]);
  } else if (i < 98304) {             // WattnT[128][256]
    int j = i - 65536;
    WattnT[j] = f2bf(W_at[(size_t)(j & 255) * 128 + (j >> 8)]);
  } else if (i < 163840) {            // WvalT[256][256]
    int j = i - 98304;
    WvalT[j] = f2bf(W_val[(size_t)(j & 255) * 256 + (j >> 8)]);
  } else if (i < 425984) {            // W1T[1024][256]
    int j = i - 163840;
    W1T[j] = f2bf(W1[(size_t)(j & 255) * 1024 + (j >> 8)]);
  } else if (i < 688128) {            // W2T[256][1024]
    int j = i - 425984;
    W2T[j] = f2bf(W2[(size_t)(j & 1023) * 256 + (j >> 10)]);
  }
}

// ---------------------------------------------------------------------------
// Projection GEMM via bf16 MFMA: C[M][NC] = A[M][256] @ BT^T + bias
// 8 waves, 512 threads.  NC=256: M-tile 32; NC=128: M-tile 64.
// EPI: 0 = +bias -> fp32;  1 = +bias, softmax per 16-group -> bf16
// ---------------------------------------------------------------------------
template <int NC, int EPI>
__global__ __launch_bounds__(512, 4) void proj_mfma(
    const unsigned short* __restrict__ A, const unsigned short* __restrict__ BT,
    const float* __restrict__ bias,
    float* __restrict__ outF, unsigned short* __restrict__ outB) {
  constexpr int MTILE = (NC == 128) ? 64 : 32;
  __shared__ __align__(16) char xs[MTILE * 512];

  const int row0 = blockIdx.x * MTILE;
  const int t = threadIdx.x;
  const int w = t >> 6, lane = t & 63;
  const int c = lane & 15, kg = lane >> 4;
  const int mbase = (NC == 128) ? (w >> 2) * 32 : 0;
  const int nbase = (NC == 128) ? (w & 3) * 32 : w * 32;

  // ---- stage A tile (bf16 global -> swizzled LDS) ----
  #pragma unroll
  for (int p = 0; p < MTILE / 16; ++p) {
    int i = t + p * 512;          // 16B chunk id
    int m = i >> 5, c16 = i & 31;
    ushort4 v0 = *(const ushort4*)(A + (size_t)(row0 + m) * 256 + c16 * 8);
    ushort4 v1 = *(const ushort4*)(A + (size_t)(row0 + m) * 256 + c16 * 8 + 4);
    int byte = (m * 512 + c16 * 16) ^ ((m & 7) << 4);
    *(ushort4*)(xs + byte) = v0;
    *(ushort4*)(xs + byte + 8) = v1;
  }
  __syncthreads();

  // ---- GEMM ----
  f32x4 acc[2][2];
  #pragma unroll
  for (int mf = 0; mf < 2; ++mf)
    #pragma unroll
    for (int nf = 0; nf < 2; ++nf) acc[mf][nf] = (f32x4){0.f, 0.f, 0.f, 0.f};
  #pragma unroll
  for (int kc = 0; kc < 8; ++kc) {
    int ab0 = ((mbase + c) * 512 + kc * 64 + kg * 16) ^ ((c & 7) << 4);
    int ab1 = ((mbase + 16 + c) * 512 + kc * 64 + kg * 16) ^ ((c & 7) << 4);
    bf16x8 a0 = *(const bf16x8*)(xs + ab0);
    bf16x8 a1 = *(const bf16x8*)(xs + ab1);
    #pragma unroll
    for (int nf = 0; nf < 2; ++nf) {
      bf16x8 b = *(const bf16x8*)(BT + (size_t)(nbase + nf * 16 + c) * 256 + kc * 32 + kg * 8);
      acc[0][nf] = __builtin_amdgcn_mfma_f32_16x16x32_bf16(a0, b, acc[0][nf], 0, 0, 0);
      acc[1][nf] = __builtin_amdgcn_mfma_f32_16x16x32_bf16(a1, b, acc[1][nf], 0, 0, 0);
    }
  }

  // ---- epilogue ----
  if (EPI == 0) {
    #pragma unroll
    for (int nf = 0; nf < 2; ++nf) {
      int n = nbase + nf * 16 + c;
      float bb = bias[n];
      #pragma unroll
      for (int mf = 0; mf < 2; ++mf)
        #pragma unroll
        for (int i = 0; i < 4; ++i) {
          int m = mbase + mf * 16 + kg * 4 + i;
          outF[(size_t)(row0 + m) * NC + n] = acc[mf][nf][i] + bb;
        }
    }
  } else {
    // softmax over 16-lane groups (one head's 16 logits per group)
    #pragma unroll
    for (int nf = 0; nf < 2; ++nf) {
      int n = nbase + nf * 16 + c;
      float bb = bias[n];
      #pragma unroll
      for (int mf = 0; mf < 2; ++mf)
        #pragma unroll
        for (int i = 0; i < 4; ++i) {
          float vv = acc[mf][nf][i] + bb;
          float mx = vv;
          mx = fmaxf(mx, __shfl_xor(mx, 1, 64));
          mx = fmaxf(mx, __shfl_xor(mx, 2, 64));
          mx = fmaxf(mx, __shfl_xor(mx, 4, 64));
          mx = fmaxf(mx, __shfl_xor(mx, 8, 64));
          float e = expf(vv - mx);
          float s = e;
          s += __shfl_xor(s, 1, 64);
          s += __shfl_xor(s, 2, 64);
          s += __shfl_xor(s, 4, 64);
          s += __shfl_xor(s, 8, 64);
          int m = mbase + mf * 16 + kg * 4 + i;
          outB[(size_t)(row0 + m) * NC + n] = f2bf(e / s);
        }
    }
  }
}

// ---------------------------------------------------------------------------
// Deformable sampling v4: 4 queries/block, float4 gathers, bf16 aw in,
// fp32 out.
// ---------------------------------------------------------------------------
__global__ __launch_bounds__(256) void msda_sample(
    const float* __restrict__ value, const float* __restrict__ off,
    const unsigned short* __restrict__ aw, const float* __restrict__ refp,
    float* __restrict__ out) {
  __shared__ __align__(16) int4   s_idx[4 * 16 * 8];   // [qi][i][h]
  __shared__ __align__(16) float4 s_w[4 * 16 * 8];
  const int t = threadIdx.x;
  const int bn0 = blockIdx.x * 4;
  const int b = bn0 / NN;

  #pragma unroll
  for (int ss = 0; ss < 2; ++ss) {
    const int s = t + ss * 256;
    const int qi = s >> 7;
    const int j  = s & 127;         // h*16 + l*4 + k
    const int bn = bn0 + qi;
    const int l  = (j >> 2) & 3;
    const int h  = j >> 4;
    const int i  = j & 15;
    const int szl = 128 >> l;
    const int st0l = (l == 0) ? 0 : (l == 1) ? 16384 : (l == 2) ? 20480 : 21504;

    float ox = off[(size_t)bn * 256 + j * 2 + 0];
    float oy = off[(size_t)bn * 256 + j * 2 + 1];
    float a  = bf2f(aw[(size_t)bn * 128 + j]);
    float rx = refp[(size_t)bn * 8 + l * 2 + 0];
    float ry = refp[(size_t)bn * 8 + l * 2 + 1];

    float x = rx * (float)szl + ox - 0.5f;
    float y = ry * (float)szl + oy - 0.5f;
    float x0f = floorf(x), y0f = floorf(y);
    float wx = x - x0f, wy = y - y0f;
    int x0 = (int)x0f, y0 = (int)y0f;
    int x1 = x0 + 1, y1 = y0 + 1;

    bool vx0 = (x0 >= 0) & (x0 < szl);
    bool vx1 = (x1 >= 0) & (x1 < szl);
    bool vy0 = (y0 >= 0) & (y0 < szl);
    bool vy1 = (y1 >= 0) & (y1 < szl);
    int cx0 = min(max(x0, 0), szl - 1);
    int cx1 = min(max(x1, 0), szl - 1);
    int cy0 = min(max(y0, 0), szl - 1);
    int cy1 = min(max(y1, 0), szl - 1);

    int base = st0l * 256 + h * 32;
    int4 iv;
    iv.x = base + (cy0 * szl + cx0) * 256;
    iv.y = base + (cy0 * szl + cx1) * 256;
    iv.z = base + (cy1 * szl + cx0) * 256;
    iv.w = base + (cy1 * szl + cx1) * 256;
    float4 wv;
    wv.x = (vx0 & vy0) ? a * (1.f - wx) * (1.f - wy) : 0.f;
    wv.y = (vx1 & vy0) ? a * wx * (1.f - wy) : 0.f;
    wv.z = (vx0 & vy1) ? a * (1.f - wx) * wy : 0.f;
    wv.w = (vx1 & vy1) ? a * wx * wy : 0.f;

    int slot = (qi * 16 + i) * 8 + h;
    s_idx[slot] = iv;
    s_w[slot] = wv;
  }
  __syncthreads();

  const int qi = t >> 6;
  const int lane = t & 63;
  const int h = lane >> 3, d4 = lane & 7;
  const float* vcol = value + (size_t)b * PP * 256 + d4 * 4;

  float4 c0 = {0.f, 0.f, 0.f, 0.f}, c1 = {0.f, 0.f, 0.f, 0.f};
  float4 c2 = {0.f, 0.f, 0.f, 0.f}, c3 = {0.f, 0.f, 0.f, 0.f};
  #pragma unroll 4
  for (int i = 0; i < 16; ++i) {
    int slot = (qi * 16 + i) * 8 + h;
    int4 iv = s_idx[slot];
    float4 wv = s_w[slot];
    float4 v0 = *(const float4*)(vcol + iv.x);
    float4 v1 = *(const float4*)(vcol + iv.y);
    float4 v2 = *(const float4*)(vcol + iv.z);
    float4 v3 = *(const float4*)(vcol + iv.w);
    c0.x += wv.x * v0.x; c0.y += wv.x * v0.y; c0.z += wv.x * v0.z; c0.w += wv.x * v0.w;
    c1.x += wv.y * v1.x; c1.y += wv.y * v1.y; c1.z += wv.y * v1.z; c1.w += wv.y * v1.w;
    c2.x += wv.z * v2.x; c2.y += wv.z * v2.y; c2.z += wv.z * v2.z; c2.w += wv.z * v2.w;
    c3.x += wv.w * v3.x; c3.y += wv.w * v3.y; c3.z += wv.w * v3.z; c3.w += wv.w * v3.w;
  }
  float4 acc;
  acc.x = (c0.x + c1.x) + (c2.x + c3.x);
  acc.y = (c0.y + c1.y) + (c2.y + c3.y);
  acc.z = (c0.z + c1.z) + (c2.z + c3.z);
  acc.w = (c0.w + c1.w) + (c2.w + c3.w);
  *(float4*)(out + (size_t)(bn0 + qi) * 256 + h * 32 + d4 * 4) = acc;
}

// ---------------------------------------------------------------------------
// Out-projection + 2q residual + LayerNorm1 -> x  (fp32 VALU, known-good)
// ---------------------------------------------------------------------------
__global__ __launch_bounds__(256) void outproj_ln(
    const float* __restrict__ A, const float* __restrict__ Wo,
    const float* __restrict__ bo, const float* __restrict__ q,
    const float* __restrict__ g1, const float* __restrict__ be1,
    float* __restrict__ Xout) {
  const int ROWS = 8;
  __shared__ float as[ROWS][CC];
  __shared__ float red[4];
  int row0 = blockIdx.x * ROWS;
  int t = threadIdx.x;
  for (int i = t; i < ROWS * CC; i += 256) {
    as[i >> 8][i & 255] = A[(size_t)(row0 + (i >> 8)) * CC + (i & 255)];
  }
  __syncthreads();
  float acc[ROWS] = {0.f, 0.f, 0.f, 0.f, 0.f, 0.f, 0.f, 0.f};
  for (int k = 0; k < CC; ++k) {
    float w = Wo[k * CC + t];
    #pragma unroll
    for (int r = 0; r < ROWS; ++r) acc[r] += as[r][k] * w;
  }
  float bb = bo[t];
  float gg = g1[t], bbe = be1[t];
  for (int r = 0; r < ROWS; ++r) {
    float val = acc[r] + bb + 2.f * q[(size_t)(row0 + r) * CC + t];
    float m = block_sum_256(val, red) * (1.f / CC);
    float dv = val - m;
    float var = block_sum_256(dv * dv, red) * (1.f / CC);
    float o = dv * rsqrtf(var + 1e-5f) * gg + bbe;
    Xout[(size_t)(row0 + r) * CC + t] = o;
  }
}

// ---------------------------------------------------------------------------
// Fused FFN v3 (BISECT LEG): hidden in 2 halves of 512 through one 32KB hs
// buffer.  LDS 48KB -> 3 blocks/CU.  acc2 persists across halves.
// ---------------------------------------------------------------------------
__global__ __launch_bounds__(512, 4) void ffn_mfma(
    const float* __restrict__ X, const unsigned short* __restrict__ W1T,
    const float* __restrict__ b1, const unsigned short* __restrict__ W2T,
    const float* __restrict__ b2, const float* __restrict__ g2,
    const float* __restrict__ be2, float* __restrict__ Out) {
  __shared__ __align__(16) char smem[49152];
  char* xs = smem;            // 32 x 512 B (bf16 X tile, swizzled)
  char* hs = smem + 16384;    // 32 x 1024 B (bf16 half-hidden, swizzled)
  float* out_s = (float*)smem;   // 32 x 260 f32 = 33280 B, aliases xs+hs

  const int row0 = blockIdx.x * 32;
  const int t = threadIdx.x;
  const int w = t >> 6, lane = t & 63;
  const int c = lane & 15, kg = lane >> 4;

  // ---- stage X tile (fp32 -> bf16 swizzled LDS) ----
  for (int i = t; i < 4096; i += 512) {
    int m = i >> 7;
    int np = i & 127;
    float2 xv = *(const float2*)(X + (size_t)(row0 + m) * 256 + np * 2);
    unsigned pk = (unsigned)f2bf(xv.x) | ((unsigned)f2bf(xv.y) << 16);
    int byte = (m * 512 + np * 4) ^ ((m & 7) << 4);
    *(unsigned*)(xs + byte) = pk;
  }
  __syncthreads();

  f32x4 acc2[2][2];   // persistent GEMM2 accumulator across halves
  #pragma unroll
  for (int mf = 0; mf < 2; ++mf)
    #pragma unroll
    for (int nf = 0; nf < 2; ++nf) acc2[mf][nf] = (f32x4){0.f, 0.f, 0.f, 0.f};

  #pragma unroll
  for (int half = 0; half < 2; ++half) {
    // ---- GEMM1 half: hid[32][512] = relu(X @ W1[:, half*512..]) ----
    f32x4 acc1[2][4];
    #pragma unroll
    for (int mf = 0; mf < 2; ++mf)
      #pragma unroll
      for (int nf = 0; nf < 4; ++nf) acc1[mf][nf] = (f32x4){0.f, 0.f, 0.f, 0.f};
    #pragma unroll
    for (int kc = 0; kc < 8; ++kc) {
      int ab0 = (c * 512 + kc * 64 + kg * 16) ^ ((c & 7) << 4);
      int ab1 = ((16 + c) * 512 + kc * 64 + kg * 16) ^ ((c & 7) << 4);
      bf16x8 a0 = *(const bf16x8*)(xs + ab0);
      bf16x8 a1 = *(const bf16x8*)(xs + ab1);
      const unsigned short* wp = W1T + (size_t)(half * 512 + w * 64) * 256 + kc * 32 + kg * 8;
      #pragma unroll
      for (int nf = 0; nf < 4; ++nf) {
        bf16x8 b = *(const bf16x8*)(wp + (size_t)(nf * 16 + c) * 256);
        acc1[0][nf] = __builtin_amdgcn_mfma_f32_16x16x32_bf16(a0, b, acc1[0][nf], 0, 0, 0);
        acc1[1][nf] = __builtin_amdgcn_mfma_f32_16x16x32_bf16(a1, b, acc1[1][nf], 0, 0, 0);
      }
    }
    __syncthreads();   // prior GEMM2's hs reads complete before overwrite
    #pragma unroll
    for (int nf = 0; nf < 4; ++nf) {
      int nl = w * 64 + nf * 16 + c;           // local col 0..511
      float bb = b1[half * 512 + nl];
      #pragma unroll
      for (int mf = 0; mf < 2; ++mf) {
        #pragma unroll
        for (int i = 0; i < 4; ++i) {
          int m = mf * 16 + kg * 4 + i;
          float v = fmaxf(acc1[mf][nf][i] + bb, 0.f);
          int byte = (m * 1024 + nl * 2) ^ ((m & 7) << 4);
          *(unsigned short*)(hs + byte) = f2bf(v);
        }
      }
    }
    __syncthreads();

    // ---- GEMM2 half: acc2 += hid_half @ W2[half*512.., :] ----
    #pragma unroll
    for (int kc = 0; kc < 16; ++kc) {
      int ab0 = (c * 1024 + kc * 64 + kg * 16) ^ ((c & 7) << 4);
      int ab1 = ((16 + c) * 1024 + kc * 64 + kg * 16) ^ ((c & 7) << 4);
      bf16x8 a0 = *(const bf16x8*)(hs + ab0);
      bf16x8 a1 = *(const bf16x8*)(hs + ab1);
      const unsigned short* wp = W2T + (size_t)(w * 32) * 1024 + half * 512 + kc * 32 + kg * 8;
      #pragma unroll
      for (int nf = 0; nf < 2; ++nf) {
        bf16x8 b = *(const bf16x8*)(wp + (size_t)(nf * 16 + c) * 1024);
        acc2[0][nf] = __builtin_amdgcn_mfma_f32_16x16x32_bf16(a0, b, acc2[0][nf], 0, 0, 0);
        acc2[1][nf] = __builtin_amdgcn_mfma_f32_16x16x32_bf16(a1, b, acc2[1][nf], 0, 0, 0);
      }
    }
  }
  __syncthreads();   // all hs/xs reads complete before out_s overwrites

  // ---- epilogue: + b2 + residual(X fp32) -> out_s ----
  #pragma unroll
  for (int nf = 0; nf < 2; ++nf) {
    int n2 = w * 32 + nf * 16 + c;
    float bb = b2[n2];
    #pragma unroll
    for (int mf = 0; mf < 2; ++mf) {
      #pragma unroll
      for (int i = 0; i < 4; ++i) {
        int m = mf * 16 + kg * 4 + i;
        out_s[m * 260 + n2] = acc2[mf][nf][i] + bb + X[(size_t)(row0 + m) * 256 + n2];
      }
    }
  }
  __syncthreads();

  // ---- LayerNorm2 per row, one wave handles 4 rows ----
  float4 gv = *(const float4*)(g2 + lane * 4);
  float4 bev = *(const float4*)(be2 + lane * 4);
  #pragma unroll
  for (int rr = 0; rr < 4; ++rr) {
    int r = w * 4 + rr;
    float4 v = *(const float4*)(out_s + r * 260 + lane * 4);
    float s = v.x + v.y + v.z + v.w;
    float s2 = v.x * v.x + v.y * v.y + v.z * v.z + v.w * v.w;
    #pragma unroll
    for (int o = 1; o < 64; o <<= 1) {
      s += __shfl_xor(s, o, 64);
      s2 += __shfl_xor(s2, o, 64);
    }
    float mean = s * (1.f / 256.f);
    float var = s2 * (1.f / 256.f) - mean * mean;
    float rstd = rsqrtf(var + 1e-5f);
    float4 o4;
    o4.x = (v.x - mean) * rstd * gv.x + bev.x;
    o4.y = (v.y - mean) * rstd * gv.y + bev.y;
    o4.z = (v.z - mean) * rstd * gv.z + bev.z;
    o4.w = (v.w - mean) * rstd * gv.w + bev.w;
    *(float4*)(Out + (size_t)(row0 + r) * 256 + lane * 4) = o4;
  }
}

// ---------------------------------------------------------------------------
// Launch
// ---------------------------------------------------------------------------
extern "C" void kernel_launch(void* const* d_in, const int* in_sizes, int n_in,
                              void* d_out, int out_size, void* d_ws, size_t ws_size,
                              hipStream_t stream) {
  const float* q     = (const float*)d_in[0];
  const float* v     = (const float*)d_in[2];
  const float* refp  = (const float*)d_in[3];
  const float* W_off = (const float*)d_in[6];
  const float* b_off = (const float*)d_in[7];
  const float* W_at  = (const float*)d_in[8];
  const float* b_at  = (const float*)d_in[9];
  const float* W_val = (const float*)d_in[10];
  const float* b_val = (const float*)d_in[11];
  const float* W_out = (const float*)d_in[12];
  const float* b_out = (const float*)d_in[13];
  const float* W1    = (const float*)d_in[14];
  const float* b1    = (const float*)d_in[15];
  const float* W2    = (const float*)d_in[16];
  const float* b2    = (const float*)d_in[17];
  const float* g1    = (const float*)d_in[18];
  const float* be1   = (const float*)d_in[19];
  const float* g2    = (const float*)d_in[20];
  const float* be2   = (const float*)d_in[21];
  float* out = (float*)d_out;

  // Workspace layout (same as R7)
  float* ws   = (float*)d_ws;
  float* valb = ws;                                   // fp32 [M][256]
  float* offb = valb + (size_t)VROWS * 256;           // fp32 [M][256]
  unsigned short* qb = (unsigned short*)(offb + (size_t)MROWS * 256); // bf16 [M][256]
  unsigned short* vb = qb + (size_t)MROWS * 256;      // bf16 [M][256]
  // msdaF (fp32 [M][256]) aliases qb+vb exactly: both dead before msda runs
  float* msdaF = (float*)qb;
  unsigned short* awb = vb + (size_t)MROWS * 256;     // bf16 [M][128]
  unsigned short* WoffT  = awb + (size_t)MROWS * 128; // [256][256]
  unsigned short* WattnT = WoffT + 65536;             // [128][256]
  unsigned short* WvalT  = WattnT + 32768;            // [256][256]
  unsigned short* W1T    = WvalT + 65536;             // [1024][256]
  unsigned short* W2T    = W1T + 262144;              // [256][1024]
  float* xb = valb;                                   // alias: valb dead after msda

  conv_bf16<<<MROWS * 256 / (256 * 8), 256, 0, stream>>>(q, v, qb, vb);
  prep_all<<<2688, 256, 0, stream>>>(W_off, W_at, W_val, W1, W2,
                                     WoffT, WattnT, WvalT, W1T, W2T);
  // value projection (fp32 out for sampling)
  proj_mfma<256, 0><<<MROWS / 32, 512, 0, stream>>>(vb, WvalT, b_val, valb, nullptr);
  // offset projection
  proj_mfma<256, 0><<<MROWS / 32, 512, 0, stream>>>(qb, WoffT, b_off, offb, nullptr);
  // attention-weight projection + softmax (bf16 out)
  proj_mfma<128, 1><<<MROWS / 64, 512, 0, stream>>>(qb, WattnT, b_at, nullptr, awb);
  // deformable bilinear sampling (fp32 out; overwrites dead qb/vb region)
  msda_sample<<<MROWS / 4, 256, 0, stream>>>(valb, offb, awb, refp, msdaF);
  // out-projection + 2q residual + LayerNorm1 (fp32 VALU, known-good)
  outproj_ln<<<MROWS / 8, 256, 0, stream>>>(msdaF, W_out, b_out, q, g1, be1, xb);
  // fused FFN v3 + residual + LayerNorm2  (the single bisect variable)
  ffn_mfma<<<MROWS / 32, 512, 0, stream>>>(xb, W1T, b1, W2T, b2, g2, be2, out);
}

// Round 10
// 537.889 us; speedup vs baseline: 1.1609x; 1.1609x over previous
//
#include <hip/hip_runtime.h>
#include <hip/hip_bf16.h>
#include <math.h>

// Problem constants (fixed by the reference file)
#define BB 2
#define NN 21760
#define CC 256
#define HH 8
#define PP 21760
#define MROWS (BB * NN)   // 43520 query rows
#define VROWS (BB * PP)   // 43520 value rows

typedef __attribute__((ext_vector_type(8))) short bf16x8;
typedef __attribute__((ext_vector_type(4))) float f32x4;

__device__ __forceinline__ unsigned short f2bf(float f) {
  unsigned u = __float_as_uint(f);
  u += 0x7fff + ((u >> 16) & 1);   // RNE
  return (unsigned short)(u >> 16);
}
__device__ __forceinline__ float bf2f(unsigned short s) {
  return __uint_as_float(((unsigned)s) << 16);
}

// ---------------------------------------------------------------------------
// Block-wide sum over 256 threads (4 waves of 64)
// ---------------------------------------------------------------------------
__device__ __forceinline__ float block_sum_256(float v, float* red) {
  #pragma unroll
  for (int o = 1; o < 64; o <<= 1) v += __shfl_xor(v, o, 64);
  int wid = threadIdx.x >> 6;
  int lane = threadIdx.x & 63;
  if (lane == 0) red[wid] = v;
  __syncthreads();
  float s = red[0] + red[1] + red[2] + red[3];
  __syncthreads();
  return s;
}

// ---------------------------------------------------------------------------
// q, v fp32 -> bf16 (row-major, same shape)
// ---------------------------------------------------------------------------
__global__ __launch_bounds__(256) void conv_bf16(
    const float* __restrict__ q, const float* __restrict__ v,
    unsigned short* __restrict__ qb, unsigned short* __restrict__ vb) {
  size_t i = ((size_t)blockIdx.x * 256 + threadIdx.x) * 8;
  float4 a0 = *(const float4*)(q + i);
  float4 a1 = *(const float4*)(q + i + 4);
  ushort4 o0 = {f2bf(a0.x), f2bf(a0.y), f2bf(a0.z), f2bf(a0.w)};
  ushort4 o1 = {f2bf(a1.x), f2bf(a1.y), f2bf(a1.z), f2bf(a1.w)};
  *(ushort4*)(qb + i) = o0;
  *(ushort4*)(qb + i + 4) = o1;
  float4 b0 = *(const float4*)(v + i);
  float4 b1 = *(const float4*)(v + i + 4);
  ushort4 p0 = {f2bf(b0.x), f2bf(b0.y), f2bf(b0.z), f2bf(b0.w)};
  ushort4 p1 = {f2bf(b1.x), f2bf(b1.y), f2bf(b1.z), f2bf(b1.w)};
  *(ushort4*)(vb + i) = p0;
  *(ushort4*)(vb + i + 4) = p1;
}

// ---------------------------------------------------------------------------
// Weights -> transposed bf16 [N][K].  (W_out stays fp32 for VALU out-proj.)
// ---------------------------------------------------------------------------
__global__ __launch_bounds__(256) void prep_all(
    const float* __restrict__ W_off, const float* __restrict__ W_at,
    const float* __restrict__ W_val,
    const float* __restrict__ W1, const float* __restrict__ W2,
    unsigned short* __restrict__ WoffT, unsigned short* __restrict__ WattnT,
    unsigned short* __restrict__ WvalT,
    unsigned short* __restrict__ W1T, unsigned short* __restrict__ W2T) {
  int i = blockIdx.x * 256 + threadIdx.x;
  if (i < 65536) {                    // WoffT[256][256]
    WoffT[i] = f2bf(W_off[(size_t)(i & 255) * 256 + (i >> 8)]);
  } else if (i < 98304) {             // WattnT[128][256]
    int j = i - 65536;
    WattnT[j] = f2bf(W_at[(size_t)(j & 255) * 128 + (j >> 8)]);
  } else if (i < 163840) {            // WvalT[256][256]
    int j = i - 98304;
    WvalT[j] = f2bf(W_val[(size_t)(j & 255) * 256 + (j >> 8)]);
  } else if (i < 425984) {            // W1T[1024][256]
    int j = i - 163840;
    W1T[j] = f2bf(W1[(size_t)(j & 255) * 1024 + (j >> 8)]);
  } else if (i < 688128) {            // W2T[256][1024]
    int j = i - 425984;
    W2T[j] = f2bf(W2[(size_t)(j & 1023) * 256 + (j >> 10)]);
  }
}

// ---------------------------------------------------------------------------
// Projection GEMM via bf16 MFMA: C[M][NC] = A[M][256] @ BT^T + bias
// 8 waves, 512 threads.  NC=256: M-tile 32; NC=128: M-tile 64.
// EPI: 0 = +bias -> fp32;  1 = +bias, softmax per 16-group -> bf16;
//      3 = +bias -> bf16
// ---------------------------------------------------------------------------
template <int NC, int EPI>
__global__ __launch_bounds__(512, 4) void proj_mfma(
    const unsigned short* __restrict__ A, const unsigned short* __restrict__ BT,
    const float* __restrict__ bias,
    float* __restrict__ outF, unsigned short* __restrict__ outB) {
  constexpr int MTILE = (NC == 128) ? 64 : 32;
  __shared__ __align__(16) char xs[MTILE * 512];

  const int row0 = blockIdx.x * MTILE;
  const int t = threadIdx.x;
  const int w = t >> 6, lane = t & 63;
  const int c = lane & 15, kg = lane >> 4;
  const int mbase = (NC == 128) ? (w >> 2) * 32 : 0;
  const int nbase = (NC == 128) ? (w & 3) * 32 : w * 32;

  // ---- stage A tile (bf16 global -> swizzled LDS) ----
  #pragma unroll
  for (int p = 0; p < MTILE / 16; ++p) {
    int i = t + p * 512;          // 16B chunk id
    int m = i >> 5, c16 = i & 31;
    ushort4 v0 = *(const ushort4*)(A + (size_t)(row0 + m) * 256 + c16 * 8);
    ushort4 v1 = *(const ushort4*)(A + (size_t)(row0 + m) * 256 + c16 * 8 + 4);
    int byte = (m * 512 + c16 * 16) ^ ((m & 7) << 4);
    *(ushort4*)(xs + byte) = v0;
    *(ushort4*)(xs + byte + 8) = v1;
  }
  __syncthreads();

  // ---- GEMM ----
  f32x4 acc[2][2];
  #pragma unroll
  for (int mf = 0; mf < 2; ++mf)
    #pragma unroll
    for (int nf = 0; nf < 2; ++nf) acc[mf][nf] = (f32x4){0.f, 0.f, 0.f, 0.f};
  #pragma unroll
  for (int kc = 0; kc < 8; ++kc) {
    int ab0 = ((mbase + c) * 512 + kc * 64 + kg * 16) ^ ((c & 7) << 4);
    int ab1 = ((mbase + 16 + c) * 512 + kc * 64 + kg * 16) ^ ((c & 7) << 4);
    bf16x8 a0 = *(const bf16x8*)(xs + ab0);
    bf16x8 a1 = *(const bf16x8*)(xs + ab1);
    #pragma unroll
    for (int nf = 0; nf < 2; ++nf) {
      bf16x8 b = *(const bf16x8*)(BT + (size_t)(nbase + nf * 16 + c) * 256 + kc * 32 + kg * 8);
      acc[0][nf] = __builtin_amdgcn_mfma_f32_16x16x32_bf16(a0, b, acc[0][nf], 0, 0, 0);
      acc[1][nf] = __builtin_amdgcn_mfma_f32_16x16x32_bf16(a1, b, acc[1][nf], 0, 0, 0);
    }
  }

  // ---- epilogue ----
  if (EPI == 0) {
    #pragma unroll
    for (int nf = 0; nf < 2; ++nf) {
      int n = nbase + nf * 16 + c;
      float bb = bias[n];
      #pragma unroll
      for (int mf = 0; mf < 2; ++mf)
        #pragma unroll
        for (int i = 0; i < 4; ++i) {
          int m = mbase + mf * 16 + kg * 4 + i;
          outF[(size_t)(row0 + m) * NC + n] = acc[mf][nf][i] + bb;
        }
    }
  } else if (EPI == 3) {
    #pragma unroll
    for (int nf = 0; nf < 2; ++nf) {
      int n = nbase + nf * 16 + c;
      float bb = bias[n];
      #pragma unroll
      for (int mf = 0; mf < 2; ++mf)
        #pragma unroll
        for (int i = 0; i < 4; ++i) {
          int m = mbase + mf * 16 + kg * 4 + i;
          outB[(size_t)(row0 + m) * NC + n] = f2bf(acc[mf][nf][i] + bb);
        }
    }
  } else {
    // softmax over 16-lane groups (one head's 16 logits per group)
    #pragma unroll
    for (int nf = 0; nf < 2; ++nf) {
      int n = nbase + nf * 16 + c;
      float bb = bias[n];
      #pragma unroll
      for (int mf = 0; mf < 2; ++mf)
        #pragma unroll
        for (int i = 0; i < 4; ++i) {
          float vv = acc[mf][nf][i] + bb;
          float mx = vv;
          mx = fmaxf(mx, __shfl_xor(mx, 1, 64));
          mx = fmaxf(mx, __shfl_xor(mx, 2, 64));
          mx = fmaxf(mx, __shfl_xor(mx, 4, 64));
          mx = fmaxf(mx, __shfl_xor(mx, 8, 64));
          float e = expf(vv - mx);
          float s = e;
          s += __shfl_xor(s, 1, 64);
          s += __shfl_xor(s, 2, 64);
          s += __shfl_xor(s, 4, 64);
          s += __shfl_xor(s, 8, 64);
          int m = mbase + mf * 16 + kg * 4 + i;
          outB[(size_t)(row0 + m) * NC + n] = f2bf(e / s);
        }
    }
  }
}

// ---------------------------------------------------------------------------
// Deformable sampling v5: 4 queries/block, bf16 value gathers (ushort4 =
// 8B per d4-lane, 64B per corner row), fp32 out.
// ---------------------------------------------------------------------------
__global__ __launch_bounds__(256) void msda_sample(
    const unsigned short* __restrict__ value, const float* __restrict__ off,
    const unsigned short* __restrict__ aw, const float* __restrict__ refp,
    float* __restrict__ out) {
  __shared__ __align__(16) int4   s_idx[4 * 16 * 8];   // [qi][i][h]
  __shared__ __align__(16) float4 s_w[4 * 16 * 8];
  const int t = threadIdx.x;
  const int bn0 = blockIdx.x * 4;
  const int b = bn0 / NN;

  #pragma unroll
  for (int ss = 0; ss < 2; ++ss) {
    const int s = t + ss * 256;
    const int qi = s >> 7;
    const int j  = s & 127;         // h*16 + l*4 + k
    const int bn = bn0 + qi;
    const int l  = (j >> 2) & 3;
    const int h  = j >> 4;
    const int i  = j & 15;
    const int szl = 128 >> l;
    const int st0l = (l == 0) ? 0 : (l == 1) ? 16384 : (l == 2) ? 20480 : 21504;

    float ox = off[(size_t)bn * 256 + j * 2 + 0];
    float oy = off[(size_t)bn * 256 + j * 2 + 1];
    float a  = bf2f(aw[(size_t)bn * 128 + j]);
    float rx = refp[(size_t)bn * 8 + l * 2 + 0];
    float ry = refp[(size_t)bn * 8 + l * 2 + 1];

    float x = rx * (float)szl + ox - 0.5f;
    float y = ry * (float)szl + oy - 0.5f;
    float x0f = floorf(x), y0f = floorf(y);
    float wx = x - x0f, wy = y - y0f;
    int x0 = (int)x0f, y0 = (int)y0f;
    int x1 = x0 + 1, y1 = y0 + 1;

    bool vx0 = (x0 >= 0) & (x0 < szl);
    bool vx1 = (x1 >= 0) & (x1 < szl);
    bool vy0 = (y0 >= 0) & (y0 < szl);
    bool vy1 = (y1 >= 0) & (y1 < szl);
    int cx0 = min(max(x0, 0), szl - 1);
    int cx1 = min(max(x1, 0), szl - 1);
    int cy0 = min(max(y0, 0), szl - 1);
    int cy1 = min(max(y1, 0), szl - 1);

    int base = st0l * 256 + h * 32;
    int4 iv;
    iv.x = base + (cy0 * szl + cx0) * 256;
    iv.y = base + (cy0 * szl + cx1) * 256;
    iv.z = base + (cy1 * szl + cx0) * 256;
    iv.w = base + (cy1 * szl + cx1) * 256;
    float4 wv;
    wv.x = (vx0 & vy0) ? a * (1.f - wx) * (1.f - wy) : 0.f;
    wv.y = (vx1 & vy0) ? a * wx * (1.f - wy) : 0.f;
    wv.z = (vx0 & vy1) ? a * (1.f - wx) * wy : 0.f;
    wv.w = (vx1 & vy1) ? a * wx * wy : 0.f;

    int slot = (qi * 16 + i) * 8 + h;
    s_idx[slot] = iv;
    s_w[slot] = wv;
  }
  __syncthreads();

  const int qi = t >> 6;
  const int lane = t & 63;
  const int h = lane >> 3, d4 = lane & 7;
  const unsigned short* vcol = value + (size_t)b * PP * 256 + d4 * 4;

  float4 c0 = {0.f, 0.f, 0.f, 0.f}, c1 = {0.f, 0.f, 0.f, 0.f};
  float4 c2 = {0.f, 0.f, 0.f, 0.f}, c3 = {0.f, 0.f, 0.f, 0.f};
  #pragma unroll 4
  for (int i = 0; i < 16; ++i) {
    int slot = (qi * 16 + i) * 8 + h;
    int4 iv = s_idx[slot];
    float4 wv = s_w[slot];
    ushort4 u0 = *(const ushort4*)(vcol + iv.x);
    ushort4 u1 = *(const ushort4*)(vcol + iv.y);
    ushort4 u2 = *(const ushort4*)(vcol + iv.z);
    ushort4 u3 = *(const ushort4*)(vcol + iv.w);
    c0.x += wv.x * bf2f(u0.x); c0.y += wv.x * bf2f(u0.y);
    c0.z += wv.x * bf2f(u0.z); c0.w += wv.x * bf2f(u0.w);
    c1.x += wv.y * bf2f(u1.x); c1.y += wv.y * bf2f(u1.y);
    c1.z += wv.y * bf2f(u1.z); c1.w += wv.y * bf2f(u1.w);
    c2.x += wv.z * bf2f(u2.x); c2.y += wv.z * bf2f(u2.y);
    c2.z += wv.z * bf2f(u2.z); c2.w += wv.z * bf2f(u2.w);
    c3.x += wv.w * bf2f(u3.x); c3.y += wv.w * bf2f(u3.y);
    c3.z += wv.w * bf2f(u3.z); c3.w += wv.w * bf2f(u3.w);
  }
  float4 acc;
  acc.x = (c0.x + c1.x) + (c2.x + c3.x);
  acc.y = (c0.y + c1.y) + (c2.y + c3.y);
  acc.z = (c0.z + c1.z) + (c2.z + c3.z);
  acc.w = (c0.w + c1.w) + (c2.w + c3.w);
  *(float4*)(out + (size_t)(bn0 + qi) * 256 + h * 32 + d4 * 4) = acc;
}

// ---------------------------------------------------------------------------
// Out-projection + 2q residual + LayerNorm1 -> x  (fp32 VALU, known-good)
// ---------------------------------------------------------------------------
__global__ __launch_bounds__(256) void outproj_ln(
    const float* __restrict__ A, const float* __restrict__ Wo,
    const float* __restrict__ bo, const float* __restrict__ q,
    const float* __restrict__ g1, const float* __restrict__ be1,
    float* __restrict__ Xout) {
  const int ROWS = 8;
  __shared__ float as[ROWS][CC];
  __shared__ float red[4];
  int row0 = blockIdx.x * ROWS;
  int t = threadIdx.x;
  for (int i = t; i < ROWS * CC; i += 256) {
    as[i >> 8][i & 255] = A[(size_t)(row0 + (i >> 8)) * CC + (i & 255)];
  }
  __syncthreads();
  float acc[ROWS] = {0.f, 0.f, 0.f, 0.f, 0.f, 0.f, 0.f, 0.f};
  for (int k = 0; k < CC; ++k) {
    float w = Wo[k * CC + t];
    #pragma unroll
    for (int r = 0; r < ROWS; ++r) acc[r] += as[r][k] * w;
  }
  float bb = bo[t];
  float gg = g1[t], bbe = be1[t];
  for (int r = 0; r < ROWS; ++r) {
    float val = acc[r] + bb + 2.f * q[(size_t)(row0 + r) * CC + t];
    float m = block_sum_256(val, red) * (1.f / CC);
    float dv = val - m;
    float var = block_sum_256(dv * dv, red) * (1.f / CC);
    float o = dv * rsqrtf(var + 1e-5f) * gg + bbe;
    Xout[(size_t)(row0 + r) * CC + t] = o;
  }
}

// ---------------------------------------------------------------------------
// Fused FFN v2 (proven, R7): M-tile=32, 8 waves, LDS 80KB.
// ---------------------------------------------------------------------------
__global__ __launch_bounds__(512, 4) void ffn_mfma(
    const float* __restrict__ X, const unsigned short* __restrict__ W1T,
    const float* __restrict__ b1, const unsigned short* __restrict__ W2T,
    const float* __restrict__ b2, const float* __restrict__ g2,
    const float* __restrict__ be2, float* __restrict__ Out) {
  __shared__ __align__(16) char smem[16384 + 65536];
  char* xs = smem;            // 32 x 512 B
  char* hs = smem + 16384;    // 32 x 2048 B
  float* out_s = (float*)(smem + 16384);   // 32 x 260 f32, aliases hs

  const int row0 = blockIdx.x * 32;
  const int t = threadIdx.x;
  const int w = t >> 6, lane = t & 63;
  const int c = lane & 15, kg = lane >> 4;

  for (int i = t; i < 4096; i += 512) {
    int m = i >> 7;
    int np = i & 127;
    float2 xv = *(const float2*)(X + (size_t)(row0 + m) * 256 + np * 2);
    unsigned pk = (unsigned)f2bf(xv.x) | ((unsigned)f2bf(xv.y) << 16);
    int byte = (m * 512 + np * 4) ^ ((m & 7) << 4);
    *(unsigned*)(xs + byte) = pk;
  }
  __syncthreads();

  // ---- GEMM1: hid[32][1024] = relu(X @ W1 + b1) ----
  f32x4 acc1[2][8];
  #pragma unroll
  for (int mf = 0; mf < 2; ++mf)
    #pragma unroll
    for (int nf = 0; nf < 8; ++nf) acc1[mf][nf] = (f32x4){0.f, 0.f, 0.f, 0.f};
  #pragma unroll
  for (int kc = 0; kc < 8; ++kc) {
    int ab0 = (c * 512 + kc * 64 + kg * 16) ^ ((c & 7) << 4);
    int ab1 = ((16 + c) * 512 + kc * 64 + kg * 16) ^ ((c & 7) << 4);
    bf16x8 a0 = *(const bf16x8*)(xs + ab0);
    bf16x8 a1 = *(const bf16x8*)(xs + ab1);
    const unsigned short* wp = W1T + (size_t)(w * 128) * 256 + kc * 32 + kg * 8;
    #pragma unroll
    for (int nf = 0; nf < 8; ++nf) {
      bf16x8 b = *(const bf16x8*)(wp + (size_t)(nf * 16 + c) * 256);
      acc1[0][nf] = __builtin_amdgcn_mfma_f32_16x16x32_bf16(a0, b, acc1[0][nf], 0, 0, 0);
      acc1[1][nf] = __builtin_amdgcn_mfma_f32_16x16x32_bf16(a1, b, acc1[1][nf], 0, 0, 0);
    }
  }
  #pragma unroll
  for (int nf = 0; nf < 8; ++nf) {
    int n = w * 128 + nf * 16 + c;
    float bb = b1[n];
    #pragma unroll
    for (int mf = 0; mf < 2; ++mf) {
      #pragma unroll
      for (int i = 0; i < 4; ++i) {
        int m = mf * 16 + kg * 4 + i;
        float v = fmaxf(acc1[mf][nf][i] + bb, 0.f);
        int byte = (m * 2048 + n * 2) ^ ((m & 7) << 4);
        *(unsigned short*)(hs + byte) = f2bf(v);
      }
    }
  }
  __syncthreads();

  // ---- GEMM2: y[32][256] = hid @ W2 ----
  f32x4 acc2[2][2];
  #pragma unroll
  for (int mf = 0; mf < 2; ++mf)
    #pragma unroll
    for (int nf = 0; nf < 2; ++nf) acc2[mf][nf] = (f32x4){0.f, 0.f, 0.f, 0.f};
  #pragma unroll
  for (int kc = 0; kc < 32; ++kc) {
    int ab0 = (c * 2048 + kc * 64 + kg * 16) ^ ((c & 7) << 4);
    int ab1 = ((16 + c) * 2048 + kc * 64 + kg * 16) ^ ((c & 7) << 4);
    bf16x8 a0 = *(const bf16x8*)(hs + ab0);
    bf16x8 a1 = *(const bf16x8*)(hs + ab1);
    const unsigned short* wp = W2T + (size_t)(w * 32) * 1024 + kc * 32 + kg * 8;
    #pragma unroll
    for (int nf = 0; nf < 2; ++nf) {
      bf16x8 b = *(const bf16x8*)(wp + (size_t)(nf * 16 + c) * 1024);
      acc2[0][nf] = __builtin_amdgcn_mfma_f32_16x16x32_bf16(a0, b, acc2[0][nf], 0, 0, 0);
      acc2[1][nf] = __builtin_amdgcn_mfma_f32_16x16x32_bf16(a1, b, acc2[1][nf], 0, 0, 0);
    }
  }
  __syncthreads();

  #pragma unroll
  for (int nf = 0; nf < 2; ++nf) {
    int n2 = w * 32 + nf * 16 + c;
    float bb = b2[n2];
    #pragma unroll
    for (int mf = 0; mf < 2; ++mf) {
      #pragma unroll
      for (int i = 0; i < 4; ++i) {
        int m = mf * 16 + kg * 4 + i;
        out_s[m * 260 + n2] = acc2[mf][nf][i] + bb + X[(size_t)(row0 + m) * 256 + n2];
      }
    }
  }
  __syncthreads();

  float4 gv = *(const float4*)(g2 + lane * 4);
  float4 bev = *(const float4*)(be2 + lane * 4);
  #pragma unroll
  for (int rr = 0; rr < 4; ++rr) {
    int r = w * 4 + rr;
    float4 v = *(const float4*)(out_s + r * 260 + lane * 4);
    float s = v.x + v.y + v.z + v.w;
    float s2 = v.x * v.x + v.y * v.y + v.z * v.z + v.w * v.w;
    #pragma unroll
    for (int o = 1; o < 64; o <<= 1) {
      s += __shfl_xor(s, o, 64);
      s2 += __shfl_xor(s2, o, 64);
    }
    float mean = s * (1.f / 256.f);
    float var = s2 * (1.f / 256.f) - mean * mean;
    float rstd = rsqrtf(var + 1e-5f);
    float4 o4;
    o4.x = (v.x - mean) * rstd * gv.x + bev.x;
    o4.y = (v.y - mean) * rstd * gv.y + bev.y;
    o4.z = (v.z - mean) * rstd * gv.z + bev.z;
    o4.w = (v.w - mean) * rstd * gv.w + bev.w;
    *(float4*)(Out + (size_t)(row0 + r) * 256 + lane * 4) = o4;
  }
}

// ---------------------------------------------------------------------------
// Launch
// ---------------------------------------------------------------------------
extern "C" void kernel_launch(void* const* d_in, const int* in_sizes, int n_in,
                              void* d_out, int out_size, void* d_ws, size_t ws_size,
                              hipStream_t stream) {
  const float* q     = (const float*)d_in[0];
  const float* v     = (const float*)d_in[2];
  const float* refp  = (const float*)d_in[3];
  const float* W_off = (const float*)d_in[6];
  const float* b_off = (const float*)d_in[7];
  const float* W_at  = (const float*)d_in[8];
  const float* b_at  = (const float*)d_in[9];
  const float* W_val = (const float*)d_in[10];
  const float* b_val = (const float*)d_in[11];
  const float* W_out = (const float*)d_in[12];
  const float* b_out = (const float*)d_in[13];
  const float* W1    = (const float*)d_in[14];
  const float* b1    = (const float*)d_in[15];
  const float* W2    = (const float*)d_in[16];
  const float* b2    = (const float*)d_in[17];
  const float* g1    = (const float*)d_in[18];
  const float* be1   = (const float*)d_in[19];
  const float* g2    = (const float*)d_in[20];
  const float* be2   = (const float*)d_in[21];
  float* out = (float*)d_out;

  // Workspace layout (same as R7/R9)
  float* ws   = (float*)d_ws;
  float* valb = ws;                                   // fp32 [M][256] region
  unsigned short* valbB = (unsigned short*)valb;      // bf16 [M][256] (first half of valb region)
  float* offb = valb + (size_t)VROWS * 256;           // fp32 [M][256]
  unsigned short* qb = (unsigned short*)(offb + (size_t)MROWS * 256); // bf16 [M][256]
  unsigned short* vb = qb + (size_t)MROWS * 256;      // bf16 [M][256]
  // msdaF (fp32 [M][256]) aliases qb+vb exactly: both dead before msda runs
  float* msdaF = (float*)qb;
  unsigned short* awb = vb + (size_t)MROWS * 256;     // bf16 [M][128]
  unsigned short* WoffT  = awb + (size_t)MROWS * 128; // [256][256]
  unsigned short* WattnT = WoffT + 65536;             // [128][256]
  unsigned short* WvalT  = WattnT + 32768;            // [256][256]
  unsigned short* W1T    = WvalT + 65536;             // [1024][256]
  unsigned short* W2T    = W1T + 262144;              // [256][1024]
  float* xb = valb;                                   // alias: valbB dead after msda

  conv_bf16<<<MROWS * 256 / (256 * 8), 256, 0, stream>>>(q, v, qb, vb);
  prep_all<<<2688, 256, 0, stream>>>(W_off, W_at, W_val, W1, W2,
                                     WoffT, WattnT, WvalT, W1T, W2T);
  // value projection (bf16 out for bf16 sampling)
  proj_mfma<256, 3><<<MROWS / 32, 512, 0, stream>>>(vb, WvalT, b_val, nullptr, valbB);
  // offset projection
  proj_mfma<256, 0><<<MROWS / 32, 512, 0, stream>>>(qb, WoffT, b_off, offb, nullptr);
  // attention-weight projection + softmax (bf16 out)
  proj_mfma<128, 1><<<MROWS / 64, 512, 0, stream>>>(qb, WattnT, b_at, nullptr, awb);
  // deformable bilinear sampling (bf16 value in, fp32 out)
  msda_sample<<<MROWS / 4, 256, 0, stream>>>(valbB, offb, awb, refp, msdaF);
  // out-projection + 2q residual + LayerNorm1 (fp32 VALU, known-good)
  outproj_ln<<<MROWS / 8, 256, 0, stream>>>(msdaF, W_out, b_out, q, g1, be1, xb);
  // fused FFN v2 + residual + LayerNorm2
  ffn_mfma<<<MROWS / 32, 512, 0, stream>>>(xb, W1T, b1, W2T, b2, g2, be2, out);
}

// Round 11
// 450.160 us; speedup vs baseline: 1.3871x; 1.1949x over previous
//
#include <hip/hip_runtime.h>
#include <hip/hip_bf16.h>
#include <math.h>

// Problem constants (fixed by the reference file)
#define BB 2
#define NN 21760
#define CC 256
#define HH 8
#define PP 21760
#define MROWS (BB * NN)   // 43520 query rows
#define VROWS (BB * PP)   // 43520 value rows

typedef __attribute__((ext_vector_type(8))) short bf16x8;
typedef __attribute__((ext_vector_type(4))) float f32x4;

__device__ __forceinline__ unsigned short f2bf(float f) {
  unsigned u = __float_as_uint(f);
  u += 0x7fff + ((u >> 16) & 1);   // RNE
  return (unsigned short)(u >> 16);
}
__device__ __forceinline__ float bf2f(unsigned short s) {
  return __uint_as_float(((unsigned)s) << 16);
}

// ---------------------------------------------------------------------------
// q, v fp32 -> bf16 (row-major, same shape)
// ---------------------------------------------------------------------------
__global__ __launch_bounds__(256) void conv_bf16(
    const float* __restrict__ q, const float* __restrict__ v,
    unsigned short* __restrict__ qb, unsigned short* __restrict__ vb) {
  size_t i = ((size_t)blockIdx.x * 256 + threadIdx.x) * 8;
  float4 a0 = *(const float4*)(q + i);
  float4 a1 = *(const float4*)(q + i + 4);
  ushort4 o0 = {f2bf(a0.x), f2bf(a0.y), f2bf(a0.z), f2bf(a0.w)};
  ushort4 o1 = {f2bf(a1.x), f2bf(a1.y), f2bf(a1.z), f2bf(a1.w)};
  *(ushort4*)(qb + i) = o0;
  *(ushort4*)(qb + i + 4) = o1;
  float4 b0 = *(const float4*)(v + i);
  float4 b1 = *(const float4*)(v + i + 4);
  ushort4 p0 = {f2bf(b0.x), f2bf(b0.y), f2bf(b0.z), f2bf(b0.w)};
  ushort4 p1 = {f2bf(b1.x), f2bf(b1.y), f2bf(b1.z), f2bf(b1.w)};
  *(ushort4*)(vb + i) = p0;
  *(ushort4*)(vb + i + 4) = p1;
}

// ---------------------------------------------------------------------------
// Weights -> transposed bf16 [N][K].  (Unchanged, proven.)
// ---------------------------------------------------------------------------
__global__ __launch_bounds__(256) void prep_all(
    const float* __restrict__ W_off, const float* __restrict__ W_at,
    const float* __restrict__ W_val,
    const float* __restrict__ W1, const float* __restrict__ W2,
    unsigned short* __restrict__ WoffT, unsigned short* __restrict__ WattnT,
    unsigned short* __restrict__ WvalT,
    unsigned short* __restrict__ W1T, unsigned short* __restrict__ W2T) {
  int i = blockIdx.x * 256 + threadIdx.x;
  if (i < 65536) {                    // WoffT[256][256]
    WoffT[i] = f2bf(W_off[(size_t)(i & 255) * 256 + (i >> 8)]);
  } else if (i < 98304) {             // WattnT[128][256]
    int j = i - 65536;
    WattnT[j] = f2bf(W_at[(size_t)(j & 255) * 128 + (j >> 8)]);
  } else if (i < 163840) {            // WvalT[256][256]
    int j = i - 98304;
    WvalT[j] = f2bf(W_val[(size_t)(j & 255) * 256 + (j >> 8)]);
  } else if (i < 425984) {            // W1T[1024][256]
    int j = i - 163840;
    W1T[j] = f2bf(W1[(size_t)(j & 255) * 1024 + (j >> 8)]);
  } else if (i < 688128) {            // W2T[256][1024]
    int j = i - 425984;
    W2T[j] = f2bf(W2[(size_t)(j & 1023) * 256 + (j >> 10)]);
  }
}

// ---------------------------------------------------------------------------
// W_out -> transposed bf16 [256][256] (separate kernel; prep_all untouched)
// ---------------------------------------------------------------------------
__global__ __launch_bounds__(256) void prep_wout(
    const float* __restrict__ W_out, unsigned short* __restrict__ WoutT) {
  int i = blockIdx.x * 256 + threadIdx.x;   // grid 256 -> i < 65536
  WoutT[i] = f2bf(W_out[(size_t)(i & 255) * 256 + (i >> 8)]);
}

// ---------------------------------------------------------------------------
// Projection GEMM via bf16 MFMA: C[M][NC] = A[M][256] @ BT^T + bias
// 8 waves, 512 threads.  NC=256: M-tile 32; NC=128: M-tile 64.
// EPI: 0 = +bias -> fp32;  1 = +bias, softmax per 16-group -> bf16;
//      3 = +bias -> bf16
// ---------------------------------------------------------------------------
template <int NC, int EPI>
__global__ __launch_bounds__(512, 4) void proj_mfma(
    const unsigned short* __restrict__ A, const unsigned short* __restrict__ BT,
    const float* __restrict__ bias,
    float* __restrict__ outF, unsigned short* __restrict__ outB) {
  constexpr int MTILE = (NC == 128) ? 64 : 32;
  __shared__ __align__(16) char xs[MTILE * 512];

  const int row0 = blockIdx.x * MTILE;
  const int t = threadIdx.x;
  const int w = t >> 6, lane = t & 63;
  const int c = lane & 15, kg = lane >> 4;
  const int mbase = (NC == 128) ? (w >> 2) * 32 : 0;
  const int nbase = (NC == 128) ? (w & 3) * 32 : w * 32;

  // ---- stage A tile (bf16 global -> swizzled LDS) ----
  #pragma unroll
  for (int p = 0; p < MTILE / 16; ++p) {
    int i = t + p * 512;          // 16B chunk id
    int m = i >> 5, c16 = i & 31;
    ushort4 v0 = *(const ushort4*)(A + (size_t)(row0 + m) * 256 + c16 * 8);
    ushort4 v1 = *(const ushort4*)(A + (size_t)(row0 + m) * 256 + c16 * 8 + 4);
    int byte = (m * 512 + c16 * 16) ^ ((m & 7) << 4);
    *(ushort4*)(xs + byte) = v0;
    *(ushort4*)(xs + byte + 8) = v1;
  }
  __syncthreads();

  // ---- GEMM ----
  f32x4 acc[2][2];
  #pragma unroll
  for (int mf = 0; mf < 2; ++mf)
    #pragma unroll
    for (int nf = 0; nf < 2; ++nf) acc[mf][nf] = (f32x4){0.f, 0.f, 0.f, 0.f};
  #pragma unroll
  for (int kc = 0; kc < 8; ++kc) {
    int ab0 = ((mbase + c) * 512 + kc * 64 + kg * 16) ^ ((c & 7) << 4);
    int ab1 = ((mbase + 16 + c) * 512 + kc * 64 + kg * 16) ^ ((c & 7) << 4);
    bf16x8 a0 = *(const bf16x8*)(xs + ab0);
    bf16x8 a1 = *(const bf16x8*)(xs + ab1);
    #pragma unroll
    for (int nf = 0; nf < 2; ++nf) {
      bf16x8 b = *(const bf16x8*)(BT + (size_t)(nbase + nf * 16 + c) * 256 + kc * 32 + kg * 8);
      acc[0][nf] = __builtin_amdgcn_mfma_f32_16x16x32_bf16(a0, b, acc[0][nf], 0, 0, 0);
      acc[1][nf] = __builtin_amdgcn_mfma_f32_16x16x32_bf16(a1, b, acc[1][nf], 0, 0, 0);
    }
  }

  // ---- epilogue ----
  if (EPI == 0) {
    #pragma unroll
    for (int nf = 0; nf < 2; ++nf) {
      int n = nbase + nf * 16 + c;
      float bb = bias[n];
      #pragma unroll
      for (int mf = 0; mf < 2; ++mf)
        #pragma unroll
        for (int i = 0; i < 4; ++i) {
          int m = mbase + mf * 16 + kg * 4 + i;
          outF[(size_t)(row0 + m) * NC + n] = acc[mf][nf][i] + bb;
        }
    }
  } else if (EPI == 3) {
    #pragma unroll
    for (int nf = 0; nf < 2; ++nf) {
      int n = nbase + nf * 16 + c;
      float bb = bias[n];
      #pragma unroll
      for (int mf = 0; mf < 2; ++mf)
        #pragma unroll
        for (int i = 0; i < 4; ++i) {
          int m = mbase + mf * 16 + kg * 4 + i;
          outB[(size_t)(row0 + m) * NC + n] = f2bf(acc[mf][nf][i] + bb);
        }
    }
  } else {
    // softmax over 16-lane groups (one head's 16 logits per group)
    #pragma unroll
    for (int nf = 0; nf < 2; ++nf) {
      int n = nbase + nf * 16 + c;
      float bb = bias[n];
      #pragma unroll
      for (int mf = 0; mf < 2; ++mf)
        #pragma unroll
        for (int i = 0; i < 4; ++i) {
          float vv = acc[mf][nf][i] + bb;
          float mx = vv;
          mx = fmaxf(mx, __shfl_xor(mx, 1, 64));
          mx = fmaxf(mx, __shfl_xor(mx, 2, 64));
          mx = fmaxf(mx, __shfl_xor(mx, 4, 64));
          mx = fmaxf(mx, __shfl_xor(mx, 8, 64));
          float e = expf(vv - mx);
          float s = e;
          s += __shfl_xor(s, 1, 64);
          s += __shfl_xor(s, 2, 64);
          s += __shfl_xor(s, 4, 64);
          s += __shfl_xor(s, 8, 64);
          int m = mbase + mf * 16 + kg * 4 + i;
          outB[(size_t)(row0 + m) * NC + n] = f2bf(e / s);
        }
    }
  }
}

// ---------------------------------------------------------------------------
// Deformable sampling v5b: 4 queries/block, bf16 value gathers, bf16 out
// (same addressing as passing fp32 store; only the pack differs).
// ---------------------------------------------------------------------------
__global__ __launch_bounds__(256) void msda_sample(
    const unsigned short* __restrict__ value, const float* __restrict__ off,
    const unsigned short* __restrict__ aw, const float* __restrict__ refp,
    unsigned short* __restrict__ out) {
  __shared__ __align__(16) int4   s_idx[4 * 16 * 8];   // [qi][i][h]
  __shared__ __align__(16) float4 s_w[4 * 16 * 8];
  const int t = threadIdx.x;
  const int bn0 = blockIdx.x * 4;
  const int b = bn0 / NN;

  #pragma unroll
  for (int ss = 0; ss < 2; ++ss) {
    const int s = t + ss * 256;
    const int qi = s >> 7;
    const int j  = s & 127;         // h*16 + l*4 + k
    const int bn = bn0 + qi;
    const int l  = (j >> 2) & 3;
    const int h  = j >> 4;
    const int i  = j & 15;
    const int szl = 128 >> l;
    const int st0l = (l == 0) ? 0 : (l == 1) ? 16384 : (l == 2) ? 20480 : 21504;

    float ox = off[(size_t)bn * 256 + j * 2 + 0];
    float oy = off[(size_t)bn * 256 + j * 2 + 1];
    float a  = bf2f(aw[(size_t)bn * 128 + j]);
    float rx = refp[(size_t)bn * 8 + l * 2 + 0];
    float ry = refp[(size_t)bn * 8 + l * 2 + 1];

    float x = rx * (float)szl + ox - 0.5f;
    float y = ry * (float)szl + oy - 0.5f;
    float x0f = floorf(x), y0f = floorf(y);
    float wx = x - x0f, wy = y - y0f;
    int x0 = (int)x0f, y0 = (int)y0f;
    int x1 = x0 + 1, y1 = y0 + 1;

    bool vx0 = (x0 >= 0) & (x0 < szl);
    bool vx1 = (x1 >= 0) & (x1 < szl);
    bool vy0 = (y0 >= 0) & (y0 < szl);
    bool vy1 = (y1 >= 0) & (y1 < szl);
    int cx0 = min(max(x0, 0), szl - 1);
    int cx1 = min(max(x1, 0), szl - 1);
    int cy0 = min(max(y0, 0), szl - 1);
    int cy1 = min(max(y1, 0), szl - 1);

    int base = st0l * 256 + h * 32;
    int4 iv;
    iv.x = base + (cy0 * szl + cx0) * 256;
    iv.y = base + (cy0 * szl + cx1) * 256;
    iv.z = base + (cy1 * szl + cx0) * 256;
    iv.w = base + (cy1 * szl + cx1) * 256;
    float4 wv;
    wv.x = (vx0 & vy0) ? a * (1.f - wx) * (1.f - wy) : 0.f;
    wv.y = (vx1 & vy0) ? a * wx * (1.f - wy) : 0.f;
    wv.z = (vx0 & vy1) ? a * (1.f - wx) * wy : 0.f;
    wv.w = (vx1 & vy1) ? a * wx * wy : 0.f;

    int slot = (qi * 16 + i) * 8 + h;
    s_idx[slot] = iv;
    s_w[slot] = wv;
  }
  __syncthreads();

  const int qi = t >> 6;
  const int lane = t & 63;
  const int h = lane >> 3, d4 = lane & 7;
  const unsigned short* vcol = value + (size_t)b * PP * 256 + d4 * 4;

  float4 c0 = {0.f, 0.f, 0.f, 0.f}, c1 = {0.f, 0.f, 0.f, 0.f};
  float4 c2 = {0.f, 0.f, 0.f, 0.f}, c3 = {0.f, 0.f, 0.f, 0.f};
  #pragma unroll 4
  for (int i = 0; i < 16; ++i) {
    int slot = (qi * 16 + i) * 8 + h;
    int4 iv = s_idx[slot];
    float4 wv = s_w[slot];
    ushort4 u0 = *(const ushort4*)(vcol + iv.x);
    ushort4 u1 = *(const ushort4*)(vcol + iv.y);
    ushort4 u2 = *(const ushort4*)(vcol + iv.z);
    ushort4 u3 = *(const ushort4*)(vcol + iv.w);
    c0.x += wv.x * bf2f(u0.x); c0.y += wv.x * bf2f(u0.y);
    c0.z += wv.x * bf2f(u0.z); c0.w += wv.x * bf2f(u0.w);
    c1.x += wv.y * bf2f(u1.x); c1.y += wv.y * bf2f(u1.y);
    c1.z += wv.y * bf2f(u1.z); c1.w += wv.y * bf2f(u1.w);
    c2.x += wv.z * bf2f(u2.x); c2.y += wv.z * bf2f(u2.y);
    c2.z += wv.z * bf2f(u2.z); c2.w += wv.z * bf2f(u2.w);
    c3.x += wv.w * bf2f(u3.x); c3.y += wv.w * bf2f(u3.y);
    c3.z += wv.w * bf2f(u3.z); c3.w += wv.w * bf2f(u3.w);
  }
  float4 acc;
  acc.x = (c0.x + c1.x) + (c2.x + c3.x);
  acc.y = (c0.y + c1.y) + (c2.y + c3.y);
  acc.z = (c0.z + c1.z) + (c2.z + c3.z);
  acc.w = (c0.w + c1.w) + (c2.w + c3.w);
  ushort4 ob = {f2bf(acc.x), f2bf(acc.y), f2bf(acc.z), f2bf(acc.w)};
  *(ushort4*)(out + (size_t)(bn0 + qi) * 256 + h * 32 + d4 * 4) = ob;
}

// ---------------------------------------------------------------------------
// Residual + LayerNorm1: x = LN(attn + 2q) * g + be.  One wave per row.
// attn (= msda@W_out + b_out) comes in fp32 from proj_mfma<256,0>.
// ---------------------------------------------------------------------------
__global__ __launch_bounds__(256) void resid_ln(
    const float* __restrict__ A, const float* __restrict__ q,
    const float* __restrict__ g, const float* __restrict__ be,
    float* __restrict__ X) {
  const int row = blockIdx.x * 4 + (threadIdx.x >> 6);
  const int lane = threadIdx.x & 63;
  const size_t base = (size_t)row * 256 + lane * 4;
  float4 a = *(const float4*)(A + base);
  float4 qv = *(const float4*)(q + base);
  float4 v;
  v.x = a.x + 2.f * qv.x;
  v.y = a.y + 2.f * qv.y;
  v.z = a.z + 2.f * qv.z;
  v.w = a.w + 2.f * qv.w;
  float s = v.x + v.y + v.z + v.w;
  float s2 = v.x * v.x + v.y * v.y + v.z * v.z + v.w * v.w;
  #pragma unroll
  for (int o = 1; o < 64; o <<= 1) {
    s += __shfl_xor(s, o, 64);
    s2 += __shfl_xor(s2, o, 64);
  }
  float mean = s * (1.f / 256.f);
  float var = s2 * (1.f / 256.f) - mean * mean;
  float rstd = rsqrtf(var + 1e-5f);
  float4 gv = *(const float4*)(g + lane * 4);
  float4 bev = *(const float4*)(be + lane * 4);
  float4 o4;
  o4.x = (v.x - mean) * rstd * gv.x + bev.x;
  o4.y = (v.y - mean) * rstd * gv.y + bev.y;
  o4.z = (v.z - mean) * rstd * gv.z + bev.z;
  o4.w = (v.w - mean) * rstd * gv.w + bev.w;
  *(float4*)(X + base) = o4;
}

// ---------------------------------------------------------------------------
// Fused FFN v2 (proven, R7/R10): M-tile=32, 8 waves, LDS 80KB.  UNCHANGED.
// ---------------------------------------------------------------------------
__global__ __launch_bounds__(512, 4) void ffn_mfma(
    const float* __restrict__ X, const unsigned short* __restrict__ W1T,
    const float* __restrict__ b1, const unsigned short* __restrict__ W2T,
    const float* __restrict__ b2, const float* __restrict__ g2,
    const float* __restrict__ be2, float* __restrict__ Out) {
  __shared__ __align__(16) char smem[16384 + 65536];
  char* xs = smem;            // 32 x 512 B
  char* hs = smem + 16384;    // 32 x 2048 B
  float* out_s = (float*)(smem + 16384);   // 32 x 260 f32, aliases hs

  const int row0 = blockIdx.x * 32;
  const int t = threadIdx.x;
  const int w = t >> 6, lane = t & 63;
  const int c = lane & 15, kg = lane >> 4;

  for (int i = t; i < 4096; i += 512) {
    int m = i >> 7;
    int np = i & 127;
    float2 xv = *(const float2*)(X + (size_t)(row0 + m) * 256 + np * 2);
    unsigned pk = (unsigned)f2bf(xv.x) | ((unsigned)f2bf(xv.y) << 16);
    int byte = (m * 512 + np * 4) ^ ((m & 7) << 4);
    *(unsigned*)(xs + byte) = pk;
  }
  __syncthreads();

  // ---- GEMM1: hid[32][1024] = relu(X @ W1 + b1) ----
  f32x4 acc1[2][8];
  #pragma unroll
  for (int mf = 0; mf < 2; ++mf)
    #pragma unroll
    for (int nf = 0; nf < 8; ++nf) acc1[mf][nf] = (f32x4){0.f, 0.f, 0.f, 0.f};
  #pragma unroll
  for (int kc = 0; kc < 8; ++kc) {
    int ab0 = (c * 512 + kc * 64 + kg * 16) ^ ((c & 7) << 4);
    int ab1 = ((16 + c) * 512 + kc * 64 + kg * 16) ^ ((c & 7) << 4);
    bf16x8 a0 = *(const bf16x8*)(xs + ab0);
    bf16x8 a1 = *(const bf16x8*)(xs + ab1);
    const unsigned short* wp = W1T + (size_t)(w * 128) * 256 + kc * 32 + kg * 8;
    #pragma unroll
    for (int nf = 0; nf < 8; ++nf) {
      bf16x8 b = *(const bf16x8*)(wp + (size_t)(nf * 16 + c) * 256);
      acc1[0][nf] = __builtin_amdgcn_mfma_f32_16x16x32_bf16(a0, b, acc1[0][nf], 0, 0, 0);
      acc1[1][nf] = __builtin_amdgcn_mfma_f32_16x16x32_bf16(a1, b, acc1[1][nf], 0, 0, 0);
    }
  }
  #pragma unroll
  for (int nf = 0; nf < 8; ++nf) {
    int n = w * 128 + nf * 16 + c;
    float bb = b1[n];
    #pragma unroll
    for (int mf = 0; mf < 2; ++mf) {
      #pragma unroll
      for (int i = 0; i < 4; ++i) {
        int m = mf * 16 + kg * 4 + i;
        float v = fmaxf(acc1[mf][nf][i] + bb, 0.f);
        int byte = (m * 2048 + n * 2) ^ ((m & 7) << 4);
        *(unsigned short*)(hs + byte) = f2bf(v);
      }
    }
  }
  __syncthreads();

  // ---- GEMM2: y[32][256] = hid @ W2 ----
  f32x4 acc2[2][2];
  #pragma unroll
  for (int mf = 0; mf < 2; ++mf)
    #pragma unroll
    for (int nf = 0; nf < 2; ++nf) acc2[mf][nf] = (f32x4){0.f, 0.f, 0.f, 0.f};
  #pragma unroll
  for (int kc = 0; kc < 32; ++kc) {
    int ab0 = (c * 2048 + kc * 64 + kg * 16) ^ ((c & 7) << 4);
    int ab1 = ((16 + c) * 2048 + kc * 64 + kg * 16) ^ ((c & 7) << 4);
    bf16x8 a0 = *(const bf16x8*)(hs + ab0);
    bf16x8 a1 = *(const bf16x8*)(hs + ab1);
    const unsigned short* wp = W2T + (size_t)(w * 32) * 1024 + kc * 32 + kg * 8;
    #pragma unroll
    for (int nf = 0; nf < 2; ++nf) {
      bf16x8 b = *(const bf16x8*)(wp + (size_t)(nf * 16 + c) * 1024);
      acc2[0][nf] = __builtin_amdgcn_mfma_f32_16x16x32_bf16(a0, b, acc2[0][nf], 0, 0, 0);
      acc2[1][nf] = __builtin_amdgcn_mfma_f32_16x16x32_bf16(a1, b, acc2[1][nf], 0, 0, 0);
    }
  }
  __syncthreads();

  #pragma unroll
  for (int nf = 0; nf < 2; ++nf) {
    int n2 = w * 32 + nf * 16 + c;
    float bb = b2[n2];
    #pragma unroll
    for (int mf = 0; mf < 2; ++mf) {
      #pragma unroll
      for (int i = 0; i < 4; ++i) {
        int m = mf * 16 + kg * 4 + i;
        out_s[m * 260 + n2] = acc2[mf][nf][i] + bb + X[(size_t)(row0 + m) * 256 + n2];
      }
    }
  }
  __syncthreads();

  float4 gv = *(const float4*)(g2 + lane * 4);
  float4 bev = *(const float4*)(be2 + lane * 4);
  #pragma unroll
  for (int rr = 0; rr < 4; ++rr) {
    int r = w * 4 + rr;
    float4 v = *(const float4*)(out_s + r * 260 + lane * 4);
    float s = v.x + v.y + v.z + v.w;
    float s2 = v.x * v.x + v.y * v.y + v.z * v.z + v.w * v.w;
    #pragma unroll
    for (int o = 1; o < 64; o <<= 1) {
      s += __shfl_xor(s, o, 64);
      s2 += __shfl_xor(s2, o, 64);
    }
    float mean = s * (1.f / 256.f);
    float var = s2 * (1.f / 256.f) - mean * mean;
    float rstd = rsqrtf(var + 1e-5f);
    float4 o4;
    o4.x = (v.x - mean) * rstd * gv.x + bev.x;
    o4.y = (v.y - mean) * rstd * gv.y + bev.y;
    o4.z = (v.z - mean) * rstd * gv.z + bev.z;
    o4.w = (v.w - mean) * rstd * gv.w + bev.w;
    *(float4*)(Out + (size_t)(row0 + r) * 256 + lane * 4) = o4;
  }
}

// ---------------------------------------------------------------------------
// Launch
// ---------------------------------------------------------------------------
extern "C" void kernel_launch(void* const* d_in, const int* in_sizes, int n_in,
                              void* d_out, int out_size, void* d_ws, size_t ws_size,
                              hipStream_t stream) {
  const float* q     = (const float*)d_in[0];
  const float* v     = (const float*)d_in[2];
  const float* refp  = (const float*)d_in[3];
  const float* W_off = (const float*)d_in[6];
  const float* b_off = (const float*)d_in[7];
  const float* W_at  = (const float*)d_in[8];
  const float* b_at  = (const float*)d_in[9];
  const float* W_val = (const float*)d_in[10];
  const float* b_val = (const float*)d_in[11];
  const float* W_out = (const float*)d_in[12];
  const float* b_out = (const float*)d_in[13];
  const float* W1    = (const float*)d_in[14];
  const float* b1    = (const float*)d_in[15];
  const float* W2    = (const float*)d_in[16];
  const float* b2    = (const float*)d_in[17];
  const float* g1    = (const float*)d_in[18];
  const float* be1   = (const float*)d_in[19];
  const float* g2    = (const float*)d_in[20];
  const float* be2   = (const float*)d_in[21];
  float* out = (float*)d_out;

  // Workspace layout (same as R10 + WoutT appended at end; no pointer shifts)
  float* ws   = (float*)d_ws;
  float* valb = ws;                                   // fp32 [M][256] region
  unsigned short* valbB = (unsigned short*)valb;      // bf16 [M][256] (first half)
  float* offb = valb + (size_t)VROWS * 256;           // fp32 [M][256]
  unsigned short* qb = (unsigned short*)(offb + (size_t)MROWS * 256); // bf16 [M][256]
  unsigned short* vb = qb + (size_t)MROWS * 256;      // bf16 [M][256]
  // msdaB (bf16 [M][256]) aliases qb exactly: qb dead before msda runs
  unsigned short* msdaB = qb;
  unsigned short* awb = vb + (size_t)MROWS * 256;     // bf16 [M][128]
  unsigned short* WoffT  = awb + (size_t)MROWS * 128; // [256][256]
  unsigned short* WattnT = WoffT + 65536;             // [128][256]
  unsigned short* WvalT  = WattnT + 32768;            // [256][256]
  unsigned short* W1T    = WvalT + 65536;             // [1024][256]
  unsigned short* W2T    = W1T + 262144;              // [256][1024]
  unsigned short* WoutT  = W2T + 262144;              // [256][256] (appended)
  float* attnb = offb;                                // alias: offb dead after msda
  float* xb = valb;                                   // alias: valbB dead after msda

  conv_bf16<<<MROWS * 256 / (256 * 8), 256, 0, stream>>>(q, v, qb, vb);
  prep_all<<<2688, 256, 0, stream>>>(W_off, W_at, W_val, W1, W2,
                                     WoffT, WattnT, WvalT, W1T, W2T);
  prep_wout<<<256, 256, 0, stream>>>(W_out, WoutT);
  // value projection (bf16 out for bf16 sampling)
  proj_mfma<256, 3><<<MROWS / 32, 512, 0, stream>>>(vb, WvalT, b_val, nullptr, valbB);
  // offset projection
  proj_mfma<256, 0><<<MROWS / 32, 512, 0, stream>>>(qb, WoffT, b_off, offb, nullptr);
  // attention-weight projection + softmax (bf16 out)
  proj_mfma<128, 1><<<MROWS / 64, 512, 0, stream>>>(qb, WattnT, b_at, nullptr, awb);
  // deformable bilinear sampling (bf16 value in, bf16 out; overwrites dead qb)
  msda_sample<<<MROWS / 4, 256, 0, stream>>>(valbB, offb, awb, refp, msdaB);
  // out-projection via proven EPI=0 core -> attn + b_out (fp32, into dead offb)
  proj_mfma<256, 0><<<MROWS / 32, 512, 0, stream>>>(msdaB, WoutT, b_out, attnb, nullptr);
  // residual + LayerNorm1 (separate, trivially-correct kernel)
  resid_ln<<<MROWS / 4, 256, 0, stream>>>(attnb, q, g1, be1, xb);
  // fused FFN v2 + residual + LayerNorm2 (unchanged)
  ffn_mfma<<<MROWS / 32, 512, 0, stream>>>(xb, W1T, b1, W2T, b2, g2, be2, out);
}